// Round 15
// baseline (200.208 us; speedup 1.0000x reference)
//
#include <hip/hip_runtime.h>
#include <hip/hip_bf16.h>

typedef short s16x8 __attribute__((ext_vector_type(8)));
typedef float f32x16 __attribute__((ext_vector_type(16)));

namespace {
constexpr int kB = 16;
constexpr int kD = 256;
constexpr int kHW = 16384;
constexpr int kM = 4096;
constexpr int kN = kB * kM;              // 65536 samples
constexpr int kWin = 1024;               // columns per window
constexpr int kNWin = kHW / kWin;        // 16 windows
constexpr int kNBlk = kB * kNWin;        // 256 blocks (1/CU)
constexpr int kKT = 16;                  // K-tile columns
constexpr int kNIter = kWin / kKT;       // 64 iterations
constexpr float kLam = 0.005f;

// LDS map (bytes):
//   ring slot s (s=0..2):  A f32 [256][16] @ s*32768 ; B f32 @ s*32768+16384
//   frag buf f (f=0,1):    A bf16 frags @ 98304 + f*16384 ; B @ +8192
//   counts int[1024]       @ 131072
constexpr int kLdsRing = 32768;
constexpr int kLdsFrag = 98304;
constexpr int kLdsCnt  = 131072;
constexpr int kLdsTot  = 135168;         // 132 KB (<=160KB/CU)

__device__ __forceinline__ unsigned short f2bf(float f) {
    union { float f; unsigned u; } x{f};
    const unsigned r = x.u + 0x7FFFu + ((x.u >> 16) & 1u);
    return (unsigned short)(r >> 16);
}
__device__ __forceinline__ float bf2f(unsigned short h) {
    union { unsigned u; float f; } x;
    x.u = ((unsigned)h) << 16;
    return x.f;
}
}

// ---------------------------------------------------------------------------
// Kernel 1: per-b histogram of flat_idx -> counts c[b][p].
// ---------------------------------------------------------------------------
__global__ __launch_bounds__(256) void count_kernel(
    const int* __restrict__ flat_idx, int* __restrict__ cnt)
{
    __shared__ int h[kHW];
    const int t = threadIdx.x;
    const int b = blockIdx.x;
    for (int i = t; i < kHW; i += 256) h[i] = 0;
    __syncthreads();
    const int* bi = flat_idx + b * kM;
    for (int i = t; i < kM; i += 256) atomicAdd(&h[bi[i]], 1);
    __syncthreads();
    int* dst = cnt + b * kHW;
    for (int i = t; i < kHW; i += 256) dst[i] = h[i];
}

// ---------------------------------------------------------------------------
// Kernel 2: fused stream + weighted Gram + stats.
// Prefetch depth decoupled from registers: raw f32 tiles staged to a
// 3-deep LDS ring via global_load_lds (no VGPR payload) -> ~96KB/CU of
// loads continuously in flight (vs ~9KB register-burst before).  Counted
// per-wave vmcnt(4) + s_barrier at iter top; lgkmcnt(0)+barrier at bottom.
// CONV converts LDS f32 -> stats + bf16 frag buffers (R9 layout); MFMA
// unchanged.  1 block/CU (132KB LDS).
// ---------------------------------------------------------------------------
__global__ __launch_bounds__(512) void fused_gram_kernel(
    const float* __restrict__ z, const float* __restrict__ zp,
    const int* __restrict__ cnt,
    __hip_bfloat16* __restrict__ partial, float* __restrict__ statsPart)
{
    __shared__ char smem[kLdsTot];

    const int bx = blockIdx.x;
    const int b = bx & (kB - 1);
    const int win0 = (bx >> 4) * kWin;
    const int t = threadIdx.x;
    const int w = t >> 6, lane = t & 63, l31 = lane & 31, half = lane >> 5;
    const int wr = w >> 2;          // 0..1  row block of 128
    const int wc = w & 3;           // 0..3  col block of 64
    const int rbase = t >> 2;       // 0..127 conv row
    const int cg = t & 3;           // 0..3   conv col group (4 f32)

    const float* zb  = z  + (size_t)b * kD * kHW;
    const float* zpb = zp + (size_t)b * kD * kHW;
    const int* cb = cnt + b * kHW + win0;

    f32x16 acc[4][2];
#pragma unroll
    for (int i = 0; i < 4; ++i)
#pragma unroll
        for (int j = 0; j < 2; ++j)
#pragma unroll
            for (int r = 0; r < 16; ++r) acc[i][j][r] = 0.f;

    float sA[2], ssA[2], sB[2], ssB[2];
#pragma unroll
    for (int q = 0; q < 2; ++q) { sA[q] = ssA[q] = sB[q] = ssB[q] = 0.f; }

    // stage counts for the whole window: 16 width-4 insts, 2 per wave
    auto STAGE_CNT = [&]() {
#pragma unroll
        for (int j = 0; j < 2; ++j) {
            const int inst = 2 * w + j;
            const int* gp = cb + inst * 64 + lane;
            __builtin_amdgcn_global_load_lds(
                (const __attribute__((address_space(1))) void*)gp,
                (__attribute__((address_space(3))) void*)(smem + kLdsCnt + inst * 256),
                4, 0, 0);
        }
    };

    // stage one f32 tile (A+B, 32KB) into ring slot kt%3: 4 insts per wave
    auto STAGE = [&](int kt) {
        char* slot = smem + (kt % 3) * kLdsRing;
        const int colb = win0 + kt * kKT + (lane & 3) * 4;
#pragma unroll
        for (int j = 0; j < 2; ++j) {
            const int c = 2 * w + j;                 // chunk 0..15 (16 rows each)
            const int row = 16 * c + (lane >> 2);
            const float* gpA = zb  + (size_t)row * kHW + colb;
            const float* gpB = zpb + (size_t)row * kHW + colb;
            __builtin_amdgcn_global_load_lds(
                (const __attribute__((address_space(1))) void*)gpA,
                (__attribute__((address_space(3))) void*)(slot + c * 1024), 16, 0, 0);
            __builtin_amdgcn_global_load_lds(
                (const __attribute__((address_space(1))) void*)gpB,
                (__attribute__((address_space(3))) void*)(slot + 16384 + c * 1024), 16, 0, 0);
        }
    };

    // convert f32 ring slot kt%3 -> frag buffer kt&1 (+stats)
    auto CONV = [&](int kt) {
        const char* Af = smem + (kt % 3) * kLdsRing;
        const char* Bf = Af + 16384;
        char* Ad = smem + kLdsFrag + (kt & 1) * 16384;
        char* Bd = Ad + 8192;
        const int4 ci = *(const int4*)(smem + kLdsCnt + ((kt * 16 + cg * 4) << 2));
        const float cf[4] = {(float)ci.x, (float)ci.y, (float)ci.z, (float)ci.w};
#pragma unroll
        for (int q = 0; q < 2; ++q) {
            const int row = rbase + 128 * q;
            const float4 va = *(const float4*)(Af + row * 64 + cg * 16);
            const float4 vb = *(const float4*)(Bf + row * 64 + cg * 16);
            const float a[4]  = {va.x, va.y, va.z, va.w};
            const float bb[4] = {vb.x, vb.y, vb.z, vb.w};
            ushort4 pa, pb;
            unsigned short* pav = (unsigned short*)&pa;
            unsigned short* pbv = (unsigned short*)&pb;
#pragma unroll
            for (int j = 0; j < 4; ++j) {
                const float wbv = cf[j] * bb[j];
                sA[q]  = fmaf(cf[j], a[j], sA[q]);
                ssA[q] = fmaf(cf[j], a[j] * a[j], ssA[q]);
                sB[q]  = fmaf(cf[j], bb[j], sB[q]);
                ssB[q] = fmaf(cf[j], bb[j] * bb[j], ssB[q]);
                pav[j] = f2bf(a[j]);    // A raw
                pbv[j] = f2bf(wbv);     // B weighted
            }
            const int off = (((cg >> 1) * 256 + row) << 4) + ((cg & 1) << 3);
            *(unsigned long long*)(Ad + off) = *(unsigned long long*)&pa;
            *(unsigned long long*)(Bd + off) = *(unsigned long long*)&pb;
        }
    };

    auto MFMA_STEP = [&](int fb) {
        const char* As = smem + kLdsFrag + fb * 16384;
        const char* Bs = As + 8192;
        s16x8 af[4], bfr[2];
#pragma unroll
        for (int rt = 0; rt < 4; ++rt) {
            const int row = 128 * wr + 32 * rt + l31;
            af[rt] = *(const s16x8*)(As + ((half * 256 + row) << 4));
        }
#pragma unroll
        for (int ct = 0; ct < 2; ++ct) {
            const int row = 64 * wc + 32 * ct + l31;
            bfr[ct] = *(const s16x8*)(Bs + ((half * 256 + row) << 4));
        }
#pragma unroll
        for (int rt = 0; rt < 4; ++rt)
#pragma unroll
            for (int ct = 0; ct < 2; ++ct)
                acc[rt][ct] = __builtin_amdgcn_mfma_f32_32x32x16_bf16(
                    af[rt], bfr[ct], acc[rt][ct], 0, 0, 0);
    };

    // ---- Prologue ----
    STAGE_CNT();
    STAGE(0);
    asm volatile("s_waitcnt vmcnt(0)" ::: "memory");
    __builtin_amdgcn_s_barrier();
    __builtin_amdgcn_sched_barrier(0);
    CONV(0);
    STAGE(1);
    STAGE(2);
    asm volatile("s_waitcnt lgkmcnt(0)" ::: "memory");
    __builtin_amdgcn_s_barrier();

    // ---- Main loop ----
    for (int kt = 0; kt < kNIter; ++kt) {
        // own 4 stage-insts of tile kt+1 must be landed; tile kt+2's 4 may fly
        if (kt <= kNIter - 3) asm volatile("s_waitcnt vmcnt(4)" ::: "memory");
        else                  asm volatile("s_waitcnt vmcnt(0)" ::: "memory");
        __builtin_amdgcn_s_barrier();
        __builtin_amdgcn_sched_barrier(0);
        if (kt + 3 < kNIter) STAGE(kt + 3);   // slot (kt+3)%3 == kt%3, dead since iter kt-1
        if (kt + 1 < kNIter) CONV(kt + 1);
        MFMA_STEP(kt & 1);
        asm volatile("s_waitcnt lgkmcnt(0)" ::: "memory");
        __builtin_amdgcn_s_barrier();
    }
    __syncthreads();   // full drain before smem reuse

    // 256x256 partial Gram in bf16
    __hip_bfloat16* out = partial + (size_t)bx * (kD * kD);
#pragma unroll
    for (int rt = 0; rt < 4; ++rt)
#pragma unroll
        for (int ct = 0; ct < 2; ++ct)
#pragma unroll
            for (int r = 0; r < 16; ++r) {
                const int row = 128 * wr + 32 * rt + (r & 3) + 8 * (r >> 2) + 4 * half;
                const int col = 64 * wc + 32 * ct + l31;
                ((unsigned short*)out)[row * kD + col] = f2bf(acc[rt][ct][r]);
            }

    // stats partial reduce via (dead) LDS: sd[256 rows][4 cg][4 kinds] = 16KB
    float* sd = (float*)smem;
#pragma unroll
    for (int q = 0; q < 2; ++q) {
        const int row = rbase + 128 * q;
        float* p = sd + (row * 4 + cg) * 4;
        p[0] = sA[q]; p[1] = ssA[q]; p[2] = sB[q]; p[3] = ssB[q];
    }
    __syncthreads();
    {
        const int row = t >> 1;
        const int pair = t & 1;
        float a0 = 0.f, a1 = 0.f;
#pragma unroll
        for (int g = 0; g < 4; ++g) {
            a0 += sd[(row * 4 + g) * 4 + 2 * pair];
            a1 += sd[(row * 4 + g) * 4 + 2 * pair + 1];
        }
        float* p = statsPart + ((size_t)bx * kD + row) * 4;
        p[2 * pair] = a0;
        p[2 * pair + 1] = a1;
    }
}

// ---------------------------------------------------------------------------
// Kernel 3: reduce bf16 partial Grams (256 x [256][256]) -> G f32;
// statsPart -> statsRed.
// ---------------------------------------------------------------------------
__global__ __launch_bounds__(256) void reduce_gram_kernel(
    const __hip_bfloat16* __restrict__ partial, const float* __restrict__ statsPart,
    float* __restrict__ G, float* __restrict__ statsRed)
{
    const int d = blockIdx.x;
    const int t = threadIdx.x;
    const int eg = t & 31;          // e-group: cols eg*8..+8
    const int cgp = t >> 5;         // 0..7

    float fa[8];
#pragma unroll
    for (int j = 0; j < 8; ++j) fa[j] = 0.f;
    const unsigned short* pbase = (const unsigned short*)partial + d * kD + eg * 8;
    for (int c0 = 0; c0 < kNBlk / 8; ++c0) {
        const int c = c0 * 8 + cgp;
        const s16x8 v = *(const s16x8*)(pbase + (size_t)c * (kD * kD));
#pragma unroll
        for (int j = 0; j < 8; ++j)
            fa[j] += bf2f(((const unsigned short*)&v)[j]);
    }
    __shared__ float sd[8][256];
#pragma unroll
    for (int j = 0; j < 8; ++j) sd[cgp][eg * 8 + j] = fa[j];
    __syncthreads();
    {
        const int e = t;
        float s = 0.f;
#pragma unroll
        for (int g = 0; g < 8; ++g) s += sd[g][e];
        G[d * kD + e] = s;
    }

    float x0 = 0.f, x1 = 0.f, x2 = 0.f, x3 = 0.f;
    if (t < kNBlk) {
        const float4 v = *(const float4*)(statsPart + ((size_t)t * kD + d) * 4);
        x0 = v.x; x1 = v.y; x2 = v.z; x3 = v.w;
    }
#pragma unroll
    for (int o = 32; o; o >>= 1) {
        x0 += __shfl_down(x0, o);
        x1 += __shfl_down(x1, o);
        x2 += __shfl_down(x2, o);
        x3 += __shfl_down(x3, o);
    }
    __shared__ float r[4][4];
    if ((t & 63) == 0) {
        r[t >> 6][0] = x0; r[t >> 6][1] = x1;
        r[t >> 6][2] = x2; r[t >> 6][3] = x3;
    }
    __syncthreads();
    if (t < 4) {
        statsRed[d * 4 + t] = r[0][t] + r[1][t] + r[2][t] + r[3][t];
    }
}

// ---------------------------------------------------------------------------
// Kernel 4: final loss (single block).
// ---------------------------------------------------------------------------
__global__ __launch_bounds__(256) void loss_kernel(
    const float* __restrict__ G, const float* __restrict__ statsRed,
    float* __restrict__ out)
{
    __shared__ float muA[kD], isA[kD], muB[kD], isB[kD];
    const int t = threadIdx.x;
    const float4 v = *(const float4*)(statsRed + t * 4);
    const float n = (float)kN;
    const float mA = v.x / n, mB = v.z / n;
    const float vA = (v.y - n * mA * mA) / (n - 1.f);
    const float vB = (v.w - n * mB * mB) / (n - 1.f);
    const float sdA = fmaxf(sqrtf(fmaxf(vA, 0.f)), 1e-6f);
    const float sdB = fmaxf(sqrtf(fmaxf(vB, 0.f)), 1e-6f);
    muA[t] = mA; isA[t] = 1.f / sdA;
    muB[t] = mB; isB[t] = 1.f / sdB;
    __syncthreads();

    float acc = 0.f;
    for (int d = 0; d < kD; ++d) {
        const int e = t;
        const float c = (G[d * kD + e] / n - muA[d] * muB[e]) * isA[d] * isB[e];
        if (d == e) { const float u = 1.f - c; acc += u * u; }
        else        { acc += kLam * c * c; }
    }
#pragma unroll
    for (int o = 32; o; o >>= 1) acc += __shfl_down(acc, o);
    __shared__ float r[4];
    if ((t & 63) == 0) r[t >> 6] = acc;
    __syncthreads();
    if (t == 0) out[0] = r[0] + r[1] + r[2] + r[3];
}

// ---------------------------------------------------------------------------
extern "C" void kernel_launch(void* const* d_in, const int* in_sizes, int n_in,
                              void* d_out, int out_size, void* d_ws, size_t ws_size,
                              hipStream_t stream) {
    const float* z  = (const float*)d_in[0];
    const float* zp = (const float*)d_in[1];
    const int* flat_idx = (const int*)d_in[2];
    float* out = (float*)d_out;

    char* ws = (char*)d_ws;
    // ws layout:
    //   [0, 1MB)        counts  int [16][16384]
    //   [1MB, 3MB)      statsPart f32 [256][256][4]
    //   [3MB, +4K)      statsRed f32 [256][4]
    //   [3MB+64K,+256K) G f32 [256][256]
    //   [16MB, 48MB)    partial bf16 [256][256][256]
    int* cnt = (int*)ws;
    float* statsPart = (float*)(ws + (size_t)1 * 1024 * 1024);
    float* statsRed  = (float*)(ws + (size_t)3 * 1024 * 1024);
    float* G = (float*)(ws + (size_t)3 * 1024 * 1024 + 64 * 1024);
    __hip_bfloat16* partial = (__hip_bfloat16*)(ws + (size_t)16 * 1024 * 1024);

    count_kernel<<<kB, 256, 0, stream>>>(flat_idx, cnt);
    fused_gram_kernel<<<kNBlk, 512, 0, stream>>>(z, zp, cnt, partial, statsPart);
    reduce_gram_kernel<<<kD, 256, 0, stream>>>(partial, statsPart, G, statsRed);
    loss_kernel<<<1, 256, 0, stream>>>(G, statsRed, out);
}